// Round 13
// baseline (578.892 us; speedup 1.0000x reference)
//
#include <hip/hip_runtime.h>
#include <hip/hip_bf16.h>
#include <stdint.h>

#define IN_F 4096
#define OUT_F 4096

typedef __attribute__((ext_vector_type(8))) __bf16 bf16x8;
typedef __attribute__((ext_vector_type(4))) float f32x4;

__device__ __forceinline__ void gl_lds_16(const void* g, void* l) {
    __builtin_amdgcn_global_load_lds((const __attribute__((address_space(1))) void*)g,
                                     (__attribute__((address_space(3))) void*)l,
                                     16, 0, 0);
}

// ---- fused: sorted-COO scatter + x fp32->bf16 cvt (R12 verified-best form:
// scatter blocks first so their latency tail hides under the BW-bound cvt) ----
// Dead ends (do not re-attempt): search-based W build (R4/R9), split dispatches
// (R7), in-GEMM A-cvt (R11: 2.2x GEMM regression).
__global__ void cvt_and_scatter(const float* __restrict__ x, __bf16* __restrict__ Xb, int n8,
                                const float* __restrict__ vals, const int* __restrict__ idx,
                                __bf16* __restrict__ W, int nnz, int scatBlocks) {
    if ((int)blockIdx.x < scatBlocks) {
        int i = blockIdx.x * blockDim.x + threadIdx.x;
        if (i >= nnz) return;
        const int id = idx[i];
        if (i > 0 && idx[i - 1] == id) return;
        float s = vals[i];
        for (int j = i + 1; j < nnz && idx[j] == id; ++j) s += vals[j];
        W[id] = (__bf16)s;
    } else {
        int i = (blockIdx.x - scatBlocks) * blockDim.x + threadIdx.x;
        if (i < n8) {
            const float4* src = (const float4*)(x + (size_t)i * 8);
            float4 v0 = src[0], v1 = src[1];
            bf16x8 o;
            o[0] = (__bf16)v0.x; o[1] = (__bf16)v0.y; o[2] = (__bf16)v0.z; o[3] = (__bf16)v0.w;
            o[4] = (__bf16)v1.x; o[5] = (__bf16)v1.y; o[6] = (__bf16)v1.z; o[7] = (__bf16)v1.w;
            *(bf16x8*)(Xb + (size_t)i * 8) = o;
        }
    }
}

// ---- GEMM: C[M,N] = A[M,K] * B[N,K]^T + bias,  bf16 in / fp32 out ----
// R13: 128x128 tile, 4 waves (2x2), 64KB LDS -> TWO blocks/CU. The R7-R12
// schedule at 256² measured 2048 cyc/tile vs 1024 MFMA-cyc: the residual is
// single-barrier-domain convergence skew (conflicts=0, vmcnt hoist ~free, all
// MFMAs acc-independent -> everything else is ruled out). Two independent
// barrier domains per CU let one block's MFMAs fill the other's barrier idle
// (m97/m114 mechanism). 256²@2 blocks is LDS+VGPR-impossible (128KB, 128 AGPR
// acc); 128²@4 waves needs ~64KB + ~175 regs -> 2 blocks/CU fits.
// Schedule IDENTICAL to R10 (verified): distance-3 prefetch, quad-buffer,
// vmcnt(4) ledger (4 VMEM/tile), chunk-XOR swizzle (same formula: row>>1&3 ==
// u>>3&3 at 4 chunks/row... 64B rows -> (u&3)^((u>>3)&3)), SGB interleave,
// hoisted end-wait, no setprio (R6), no wave-role branches (R8), no
// sched_barrier(0) (R5).
#define BM 128
#define BN 128
#define BK 32
#define NT (IN_F / BK)   // 128 K-tiles

__global__ __launch_bounds__(256, 2) void gemm_bf16_bt(
    const __bf16* __restrict__ A, const __bf16* __restrict__ B,
    const float* __restrict__ bias, float* __restrict__ C,
    int M, int N, int K)
{
    __shared__ __align__(128) __bf16 lds[4][8192];   // 4 x 16KB = 64KB

    const int t256 = threadIdx.x;          // 0..255
    const int wave = t256 >> 6;            // 0..3
    const int lane = t256 & 63;
    const int wm = wave >> 1;              // 0..1  (M half)
    const int wn = wave & 1;               // 0..1  (N half)
    const int lq = lane >> 4;              // 0..3
    const int lr = lane & 15;              // 0..15

    // XCD swizzle: grid 2048 = 8 XCDs x 256 contiguous slots; nt fastest.
    const int bid  = blockIdx.x;
    const int wgid = (bid & 7) * 256 + (bid >> 3);
    const int mt = wgid >> 5;              // 0..63
    const int nt = wgid & 31;              // 0..31
    const int tileM = mt * BM;
    const int tileN = nt * BN;

    // staging: 8KB per matrix-half-pair; thread u covers row u>>2 (0..63),
    // 16B chunk u&3. DEST linear (u*16B); SOURCE chunk is the swizzle-inverse
    // c = (u&3) ^ ((row>>1)&3) = (u&3) ^ ((u>>3)&3)  [row = u>>2].
    const int srow = t256 >> 2;            // 0..63
    const int scol = ((t256 & 3) ^ ((t256 >> 3) & 3)) * 8;

    const __bf16* gA0 = A + (size_t)(tileM + srow) * K + scol;        // rows 0..63
    const __bf16* gA1 = A + (size_t)(tileM + 64 + srow) * K + scol;   // rows 64..127
    const __bf16* gB0 = B + (size_t)(tileN + srow) * K + scol;
    const __bf16* gB1 = B + (size_t)(tileN + 64 + srow) * K + scol;

#define STAGE_A(buf, k0) do { \
        gl_lds_16(gA0 + (k0), &lds[buf][0]    + t256 * 8); \
        gl_lds_16(gA1 + (k0), &lds[buf][2048] + t256 * 8); } while (0)
#define STAGE_B(buf, k0) do { \
        gl_lds_16(gB0 + (k0), &lds[buf][4096]        + t256 * 8); \
        gl_lds_16(gB1 + (k0), &lds[buf][4096 + 2048] + t256 * 8); } while (0)

    // fragment read offsets with matching XOR (row bases wm*64, mi*16 are
    // multiples of 16 -> ((row>>1)&3) == ((lr>>1)&3)):
    const int cswz = (lq ^ ((lr >> 1) & 3)) * 8;
    const int aoff = (wm * 64 + lr) * BK + cswz;             // fa[mi] at +mi*512
    const int boff = 4096 + (wn * 64 + lr) * BK + cswz;      // fb[ni] at +ni*512

    f32x4 acc[4][4] = {};
    bf16x8 fa0[4], fb0[4], fa1[4], fb1[4];

#define MM1(FAc, FBc, MI) do {                                                  \
        _Pragma("unroll") for (int ni_ = 0; ni_ < 4; ++ni_)                     \
            acc[MI][ni_] = __builtin_amdgcn_mfma_f32_16x16x32_bf16(             \
                FAc[MI], FBc[ni_], acc[MI][ni_], 0, 0, 0);                      \
    } while (0)

// main-loop tile: 4 VMEM, 8 DS_READ, 16 MFMA, interleaved + SGB prescription.
#define TILE_MAIN(T, FAc, FBc, FAn, FBn) do {                                   \
        const int t_ = (T);                                                     \
        const int pb_ = (t_ + 3) & 3; const int pk_ = (t_ + 3) * BK;            \
        const __bf16* nb_ = &lds[(t_ + 1) & 3][0];                              \
        /* ---- region 1: 4 VMEM, 8 DS, 12 MFMA ---- */                         \
        STAGE_A(pb_, pk_);                                                      \
        FAn[0] = *(const bf16x8*)&nb_[aoff];                                    \
        FBn[0] = *(const bf16x8*)&nb_[boff];                                    \
        MM1(FAc, FBc, 0);                                                       \
        STAGE_B(pb_, pk_);                                                      \
        FAn[1] = *(const bf16x8*)&nb_[aoff + 512];                              \
        FBn[1] = *(const bf16x8*)&nb_[boff + 512];                              \
        MM1(FAc, FBc, 1);                                                       \
        FAn[2] = *(const bf16x8*)&nb_[aoff + 1024];                             \
        FBn[2] = *(const bf16x8*)&nb_[boff + 1024];                             \
        MM1(FAc, FBc, 2);                                                       \
        FAn[3] = *(const bf16x8*)&nb_[aoff + 1536];                             \
        FBn[3] = *(const bf16x8*)&nb_[boff + 1536];                             \
        __builtin_amdgcn_sched_group_barrier(0x030, 2, 0); /* 2 VMEM */         \
        __builtin_amdgcn_sched_group_barrier(0x100, 2, 0); /* 2 DS   */         \
        __builtin_amdgcn_sched_group_barrier(0x008, 4, 0); /* 4 MFMA */         \
        __builtin_amdgcn_sched_group_barrier(0x030, 2, 0);                      \
        __builtin_amdgcn_sched_group_barrier(0x100, 2, 0);                      \
        __builtin_amdgcn_sched_group_barrier(0x008, 4, 0);                      \
        __builtin_amdgcn_sched_group_barrier(0x100, 2, 0);                      \
        __builtin_amdgcn_sched_group_barrier(0x008, 4, 0);                      \
        __builtin_amdgcn_sched_group_barrier(0x100, 2, 0);                      \
        /* ---- hoisted wait: overlaps final MFMA group ---- */                 \
        asm volatile("s_waitcnt vmcnt(4)" ::: "memory");                        \
        /* ---- region 2: 4 MFMA (no VMEM -> certification intact) ---- */      \
        MM1(FAc, FBc, 3);                                                       \
        __builtin_amdgcn_sched_group_barrier(0x008, 4, 0);                      \
        __builtin_amdgcn_s_barrier();                                           \
        asm volatile("" ::: "memory");                                          \
    } while (0)

// tail tile: literal T -> all conditionals fold at compile time.
#define TILE(T, FAc, FBc, FAn, FBn) do {                                        \
        const int t_ = (T);                                                     \
        if (t_ + 3 < NT) {                                                      \
            const int pb_ = (t_ + 3) & 3; const int pk_ = (t_ + 3) * BK;        \
            STAGE_A(pb_, pk_); STAGE_B(pb_, pk_);                               \
        }                                                                       \
        if (t_ + 1 < NT) {                                                      \
            const __bf16* nb_ = &lds[(t_ + 1) & 3][0];                          \
            _Pragma("unroll") for (int mi = 0; mi < 4; ++mi)                    \
                FAn[mi] = *(const bf16x8*)&nb_[aoff + mi * 512];                \
            _Pragma("unroll") for (int ni = 0; ni < 4; ++ni)                    \
                FBn[ni] = *(const bf16x8*)&nb_[boff + ni * 512];                \
        }                                                                       \
        _Pragma("unroll") for (int mi = 0; mi < 4; ++mi)                        \
            _Pragma("unroll") for (int ni = 0; ni < 4; ++ni)                    \
                acc[mi][ni] = __builtin_amdgcn_mfma_f32_16x16x32_bf16(          \
                    FAc[mi], FBc[ni], acc[mi][ni], 0, 0, 0);                    \
        if (t_ < NT - 3)       asm volatile("s_waitcnt vmcnt(4)" ::: "memory"); \
        else if (t_ == NT - 3) asm volatile("s_waitcnt vmcnt(0)" ::: "memory"); \
        if (t_ < NT - 1) {                                                      \
            __builtin_amdgcn_s_barrier();                                       \
            asm volatile("" ::: "memory");                                      \
        }                                                                       \
    } while (0)

    // ---- prologue: stage 0,1,2; certify stages 0+1 for ALL waves; frags(0) ----
    STAGE_A(0, 0);   STAGE_B(0, 0);
    STAGE_A(1, 32);  STAGE_B(1, 32);
    STAGE_A(2, 64);  STAGE_B(2, 64);
    asm volatile("s_waitcnt vmcnt(4)" ::: "memory");
    __builtin_amdgcn_s_barrier();
    asm volatile("" ::: "memory");
    {
        const __bf16* nb_ = &lds[0][0];
#pragma unroll
        for (int mi = 0; mi < 4; ++mi) fa0[mi] = *(const bf16x8*)&nb_[aoff + mi * 512];
#pragma unroll
        for (int ni = 0; ni < 4; ++ni) fb0[ni] = *(const bf16x8*)&nb_[boff + ni * 512];
    }

    // main loop: tiles 0..123 (t+3 <= 126 < NT and t+1 <= 124 < NT always)
    for (int t = 0; t < 124; t += 2) {
        TILE_MAIN(t,     fa0, fb0, fa1, fb1);
        TILE_MAIN(t + 1, fa1, fb1, fa0, fb0);
    }
    // tail: tiles 124..127, literal-folded conditionals
    TILE(124, fa0, fb0, fa1, fb1);
    TILE(125, fa1, fb1, fa0, fb0);
    TILE(126, fa0, fb0, fa1, fb1);
    TILE(127, fa1, fb1, fa0, fb0);

    // ---- epilogue: C/D layout col=lane&15, row=(lane>>4)*4+reg  [m89-verified] ----
    float bv[4];
#pragma unroll
    for (int ni = 0; ni < 4; ++ni) bv[ni] = bias[tileN + wn * 64 + ni * 16 + lr];
#pragma unroll
    for (int mi = 0; mi < 4; ++mi) {
#pragma unroll
        for (int ni = 0; ni < 4; ++ni) {
            const int gn = tileN + wn * 64 + ni * 16 + lr;
#pragma unroll
            for (int r = 0; r < 4; ++r) {
                const int gm = tileM + wm * 64 + mi * 16 + lq * 4 + r;
                C[(size_t)gm * N + gn] = acc[mi][ni][r] + bv[ni];
            }
        }
    }
#undef TILE
#undef TILE_MAIN
#undef MM1
#undef STAGE_A
#undef STAGE_B
}

extern "C" void kernel_launch(void* const* d_in, const int* in_sizes, int n_in,
                              void* d_out, int out_size, void* d_ws, size_t ws_size,
                              hipStream_t stream) {
    const float* x    = (const float*)d_in[0];   // (4,2048,4096) fp32
    const float* vals = (const float*)d_in[1];   // (NNZ,) fp32
    const float* bias = (const float*)d_in[2];   // (4096,) fp32
    const int*   idx  = (const int*)d_in[3];     // (NNZ,) sorted flat indices
    float* out = (float*)d_out;                  // (4,2048,4096) fp32

    const int nnz = in_sizes[1];
    const int K = IN_F, N = OUT_F;
    const int M = in_sizes[0] / K;               // 8192

    // workspace: [0,32M) W bf16 | [32M,96M) x bf16
    char* ws = (char*)d_ws;
    __bf16* Wb = (__bf16*)ws;
    __bf16* Xb = (__bf16*)(ws + (size_t)32 * 1024 * 1024);

    const int wElems = N * K;                    // 16777216
    const int xElems = M * K;                    // 33554432
    const int n8 = xElems / 8;                   // 4194304 cvt threads
    const int cvtBlocks = n8 / 256;              // 16384
    const int scatBlocks = (nnz + 255) / 256;    // 6554

    hipMemsetAsync(Wb, 0, (size_t)wElems * sizeof(__bf16), stream);
    cvt_and_scatter<<<scatBlocks + cvtBlocks, 256, 0, stream>>>(
        x, Xb, n8, vals, idx, Wb, nnz, scatBlocks);

    gemm_bf16_bt<<<(M / BM) * (N / BN), 256, 0, stream>>>(Xb, Wb, bias, out, M, N, K);
}

// Round 14
// 447.140 us; speedup vs baseline: 1.2947x; 1.2947x over previous
//
#include <hip/hip_runtime.h>
#include <hip/hip_bf16.h>
#include <stdint.h>

#define IN_F 4096
#define OUT_F 4096

typedef __attribute__((ext_vector_type(8))) __bf16 bf16x8;
typedef __attribute__((ext_vector_type(4))) float f32x4;

__device__ __forceinline__ void gl_lds_16(const void* g, void* l) {
    __builtin_amdgcn_global_load_lds((const __attribute__((address_space(1))) void*)g,
                                     (__attribute__((address_space(3))) void*)l,
                                     16, 0, 0);
}

// ---- fused: sorted-COO scatter + x fp32->bf16 cvt ----
// Verified-best pre-pass (R12): scatter blocks FIRST so their latency tail
// hides under the BW-bound cvt (+11.5us vs cvt-first).
// Dead ends (do not re-attempt): search-based W build (R4 block-level, R9
// thread-level: both lost 40-50us); split dispatches (R7: +9us); in-GEMM
// A-cvt (R11: GEMM 2.2x regression).
__global__ void cvt_and_scatter(const float* __restrict__ x, __bf16* __restrict__ Xb, int n8,
                                const float* __restrict__ vals, const int* __restrict__ idx,
                                __bf16* __restrict__ W, int nnz, int scatBlocks) {
    if ((int)blockIdx.x < scatBlocks) {
        // flat_idx sorted -> duplicate runs adjacent; run owner sums fp32, stores bf16.
        int i = blockIdx.x * blockDim.x + threadIdx.x;
        if (i >= nnz) return;
        const int id = idx[i];
        if (i > 0 && idx[i - 1] == id) return;
        float s = vals[i];
        for (int j = i + 1; j < nnz && idx[j] == id; ++j) s += vals[j];
        W[id] = (__bf16)s;
    } else {
        int i = (blockIdx.x - scatBlocks) * blockDim.x + threadIdx.x;
        if (i < n8) {
            const float4* src = (const float4*)(x + (size_t)i * 8);
            float4 v0 = src[0], v1 = src[1];
            bf16x8 o;
            o[0] = (__bf16)v0.x; o[1] = (__bf16)v0.y; o[2] = (__bf16)v0.z; o[3] = (__bf16)v0.w;
            o[4] = (__bf16)v1.x; o[5] = (__bf16)v1.y; o[6] = (__bf16)v1.z; o[7] = (__bf16)v1.w;
            *(bf16x8*)(Xb + (size_t)i * 8) = o;
        }
    }
}

// ---- GEMM: C[M,N] = A[M,K] * B[N,K]^T + bias,  bf16 in / fp32 out ----
// Verified-best GEMM (R10/R12: 212-215us, 1287 TF, MfmaUtil 59, conflicts 0 —
// within 5% of the m201 plain-HIP structure ceiling of 62%).
// 256x256 tile, BK=32, 8 waves (2Mx4N), quad-buffered LDS, prefetch distance 3,
// chunk-XOR swizzle, register-double-buffered fragments, SGB interleave,
// hoisted end-of-tile vmcnt(4).
// Hard boundaries established this session (do NOT re-attempt):
//   R5:  sched_barrier(0) read-pinning -> LDS-queue backpressure, serial pipes.
//   R6:  setprio inside loop -> splits SGB scheduling region, interleave dies.
//   R8:  per-wave role if/else -> loop state spills to scratch (14x).
//   R11: in-GEMM fp32->bf16 A-staging (reg->ds_write) -> 2.2x regression.
//   R13: 128² tile for 2 blocks/CU -> reuse loss makes it HBM-bound (FETCH
//        295MB->1.07GB, 42% peak BW, MfmaUtil 33). 256² reuse is load-bearing;
//        2 blocks/CU at 256² is LDS-impossible (>=96KB for depth>=2 pipeline).
#define BM 256
#define BN 256
#define BK 32
#define NT (IN_F / BK)   // 128 K-tiles

__global__ __launch_bounds__(512, 2) void gemm_bf16_bt(
    const __bf16* __restrict__ A, const __bf16* __restrict__ B,
    const float* __restrict__ bias, float* __restrict__ C,
    int M, int N, int K)
{
    __shared__ __align__(128) __bf16 lds[4][16384];

    const int t512 = threadIdx.x;          // 0..511
    const int wave = t512 >> 6;            // 0..7
    const int lane = t512 & 63;
    const int wm = wave >> 2;              // 0..1  (M half)
    const int wn = wave & 3;               // 0..3  (N quarter)
    const int lq = lane >> 4;              // 0..3
    const int lr = lane & 15;              // 0..15

    // XCD swizzle: grid is exactly 512 = 8 XCDs x 64 contiguous slots
    const int bid  = blockIdx.x;
    const int wgid = (bid & 7) * 64 + (bid >> 3);
    const int mt = wgid >> 4;              // 0..31
    const int nt = wgid & 15;              // 0..15
    const int tileM = mt * BM;
    const int tileN = nt * BN;

    // staging: thread u covers row u>>2; DEST chunk u&3 linear (global_load_lds),
    // SOURCE chunk swizzle-inverse: c = (u&3) ^ ((row>>1)&3) = (u&3) ^ ((u>>3)&3).
    const int srow = t512 >> 2;            // 0..127
    const int scol = ((t512 & 3) ^ ((t512 >> 3) & 3)) * 8;

    const __bf16* gA0 = A + (size_t)(tileM + srow) * K + scol;
    const __bf16* gA1 = A + (size_t)(tileM + 128 + srow) * K + scol;
    const __bf16* gB0 = B + (size_t)(tileN + srow) * K + scol;
    const __bf16* gB1 = B + (size_t)(tileN + 128 + srow) * K + scol;

#define STAGE_A(buf, k0) do { \
        gl_lds_16(gA0 + (k0), &lds[buf][0]    + t512 * 8); \
        gl_lds_16(gA1 + (k0), &lds[buf][4096] + t512 * 8); } while (0)
#define STAGE_B(buf, k0) do { \
        gl_lds_16(gB0 + (k0), &lds[buf][8192]         + t512 * 8); \
        gl_lds_16(gB1 + (k0), &lds[buf][8192 + 4096]  + t512 * 8); } while (0)

    // fragment read offsets with matching XOR (row bases are multiples of 16):
    const int cswz = (lq ^ ((lr >> 1) & 3)) * 8;
    const int aoff = (wm * 128 + lr) * BK + cswz;            // fa[mi] at +mi*512
    const int boff = 8192 + (wn * 64 + lr) * BK + cswz;      // fb[ni] at +ni*512

    f32x4 acc[8][4] = {};
    bf16x8 fa0[8], fb0[4], fa1[8], fb1[4];

#define MM2(FAc, FBc, MI0, MI1) do {                                            \
        _Pragma("unroll") for (int ni_ = 0; ni_ < 4; ++ni_)                     \
            acc[MI0][ni_] = __builtin_amdgcn_mfma_f32_16x16x32_bf16(            \
                FAc[MI0], FBc[ni_], acc[MI0][ni_], 0, 0, 0);                    \
        _Pragma("unroll") for (int ni_ = 0; ni_ < 4; ++ni_)                     \
            acc[MI1][ni_] = __builtin_amdgcn_mfma_f32_16x16x32_bf16(            \
                FAc[MI1], FBc[ni_], acc[MI1][ni_], 0, 0, 0);                    \
    } while (0)

// main-loop tile (tiles 0..123: always stage + always read-ahead), interleaved.
#define TILE_MAIN(T, FAc, FBc, FAn, FBn) do {                                   \
        const int t_ = (T);                                                     \
        const int pb_ = (t_ + 3) & 3; const int pk_ = (t_ + 3) * BK;            \
        const __bf16* nb_ = &lds[(t_ + 1) & 3][0];                              \
        /* ---- region 1: 4 VMEM, 12 DS, 24 MFMA ---- */                        \
        STAGE_A(pb_, pk_);                                                      \
        FAn[0] = *(const bf16x8*)&nb_[aoff];                                    \
        FAn[1] = *(const bf16x8*)&nb_[aoff + 512];                              \
        FBn[0] = *(const bf16x8*)&nb_[boff];                                    \
        MM2(FAc, FBc, 0, 1);                                                    \
        STAGE_B(pb_, pk_);                                                      \
        FBn[1] = *(const bf16x8*)&nb_[boff + 512];                              \
        FBn[2] = *(const bf16x8*)&nb_[boff + 1024];                             \
        FBn[3] = *(const bf16x8*)&nb_[boff + 1536];                             \
        MM2(FAc, FBc, 2, 3);                                                    \
        FAn[2] = *(const bf16x8*)&nb_[aoff + 1024];                             \
        FAn[3] = *(const bf16x8*)&nb_[aoff + 1536];                             \
        FAn[4] = *(const bf16x8*)&nb_[aoff + 2048];                             \
        MM2(FAc, FBc, 4, 5);                                                    \
        FAn[5] = *(const bf16x8*)&nb_[aoff + 2560];                             \
        FAn[6] = *(const bf16x8*)&nb_[aoff + 3072];                             \
        FAn[7] = *(const bf16x8*)&nb_[aoff + 3584];                             \
        __builtin_amdgcn_sched_group_barrier(0x030, 2, 0); /* 2 VMEM  */        \
        __builtin_amdgcn_sched_group_barrier(0x100, 3, 0); /* 3 DS_rd */        \
        __builtin_amdgcn_sched_group_barrier(0x008, 8, 0); /* 8 MFMA  */        \
        __builtin_amdgcn_sched_group_barrier(0x030, 2, 0);                      \
        __builtin_amdgcn_sched_group_barrier(0x100, 3, 0);                      \
        __builtin_amdgcn_sched_group_barrier(0x008, 8, 0);                      \
        __builtin_amdgcn_sched_group_barrier(0x100, 3, 0);                      \
        __builtin_amdgcn_sched_group_barrier(0x008, 8, 0);                      \
        __builtin_amdgcn_sched_group_barrier(0x100, 3, 0);                      \
        /* ---- hoisted wait: overlaps with final MFMA group ---- */            \
        asm volatile("s_waitcnt vmcnt(4)" ::: "memory");                        \
        /* ---- region 2: 8 MFMA (no VMEM -> certification intact) ---- */      \
        MM2(FAc, FBc, 6, 7);                                                    \
        __builtin_amdgcn_sched_group_barrier(0x008, 8, 0);                      \
        __builtin_amdgcn_s_barrier();                                           \
        asm volatile("" ::: "memory");                                          \
    } while (0)

// tail tile: literal T -> all conditionals fold at compile time.
#define TILE(T, FAc, FBc, FAn, FBn) do {                                        \
        const int t_ = (T);                                                     \
        if (t_ + 3 < NT) {                                                      \
            const int pb_ = (t_ + 3) & 3; const int pk_ = (t_ + 3) * BK;        \
            STAGE_A(pb_, pk_); STAGE_B(pb_, pk_);                               \
        }                                                                       \
        if (t_ + 1 < NT) {                                                      \
            const __bf16* nb_ = &lds[(t_ + 1) & 3][0];                          \
            _Pragma("unroll") for (int mi = 0; mi < 8; ++mi)                    \
                FAn[mi] = *(const bf16x8*)&nb_[aoff + mi * 512];                \
            _Pragma("unroll") for (int ni = 0; ni < 4; ++ni)                    \
                FBn[ni] = *(const bf16x8*)&nb_[boff + ni * 512];                \
        }                                                                       \
        _Pragma("unroll") for (int mi = 0; mi < 8; ++mi)                        \
            _Pragma("unroll") for (int ni = 0; ni < 4; ++ni)                    \
                acc[mi][ni] = __builtin_amdgcn_mfma_f32_16x16x32_bf16(          \
                    FAc[mi], FBc[ni], acc[mi][ni], 0, 0, 0);                    \
        if (t_ < NT - 3)       asm volatile("s_waitcnt vmcnt(4)" ::: "memory"); \
        else if (t_ == NT - 3) asm volatile("s_waitcnt vmcnt(0)" ::: "memory"); \
        if (t_ < NT - 1) {                                                      \
            __builtin_amdgcn_s_barrier();                                       \
            asm volatile("" ::: "memory");                                      \
        }                                                                       \
    } while (0)

    // ---- prologue: stage 0,1,2; certify stages 0+1 for ALL waves; frags(0) ----
    STAGE_A(0, 0);   STAGE_B(0, 0);
    STAGE_A(1, 32);  STAGE_B(1, 32);
    STAGE_A(2, 64);  STAGE_B(2, 64);
    asm volatile("s_waitcnt vmcnt(4)" ::: "memory");
    __builtin_amdgcn_s_barrier();
    asm volatile("" ::: "memory");
    {
        const __bf16* nb_ = &lds[0][0];
#pragma unroll
        for (int mi = 0; mi < 8; ++mi) fa0[mi] = *(const bf16x8*)&nb_[aoff + mi * 512];
#pragma unroll
        for (int ni = 0; ni < 4; ++ni) fb0[ni] = *(const bf16x8*)&nb_[boff + ni * 512];
    }

    // main loop: tiles 0..123 (t+3 <= 126 < NT and t+1 <= 124 < NT always)
    for (int t = 0; t < 124; t += 2) {
        TILE_MAIN(t,     fa0, fb0, fa1, fb1);
        TILE_MAIN(t + 1, fa1, fb1, fa0, fb0);
    }
    // tail: tiles 124..127, literal-folded conditionals
    TILE(124, fa0, fb0, fa1, fb1);
    TILE(125, fa1, fb1, fa0, fb0);
    TILE(126, fa0, fb0, fa1, fb1);
    TILE(127, fa1, fb1, fa0, fb0);

    // ---- epilogue: C/D layout col=lane&15, row=(lane>>4)*4+reg  [m89-verified] ----
    float bv[4];
#pragma unroll
    for (int ni = 0; ni < 4; ++ni) bv[ni] = bias[tileN + wn * 64 + ni * 16 + lr];
#pragma unroll
    for (int mi = 0; mi < 8; ++mi) {
#pragma unroll
        for (int ni = 0; ni < 4; ++ni) {
            const int gn = tileN + wn * 64 + ni * 16 + lr;
#pragma unroll
            for (int r = 0; r < 4; ++r) {
                const int gm = tileM + wm * 128 + mi * 16 + lq * 4 + r;
                C[(size_t)gm * N + gn] = acc[mi][ni][r] + bv[ni];
            }
        }
    }
#undef TILE
#undef TILE_MAIN
#undef MM2
#undef STAGE_A
#undef STAGE_B
}

extern "C" void kernel_launch(void* const* d_in, const int* in_sizes, int n_in,
                              void* d_out, int out_size, void* d_ws, size_t ws_size,
                              hipStream_t stream) {
    const float* x    = (const float*)d_in[0];   // (4,2048,4096) fp32
    const float* vals = (const float*)d_in[1];   // (NNZ,) fp32
    const float* bias = (const float*)d_in[2];   // (4096,) fp32
    const int*   idx  = (const int*)d_in[3];     // (NNZ,) sorted flat indices
    float* out = (float*)d_out;                  // (4,2048,4096) fp32

    const int nnz = in_sizes[1];
    const int K = IN_F, N = OUT_F;
    const int M = in_sizes[0] / K;               // 8192

    // workspace: [0,32M) W bf16 | [32M,96M) x bf16
    char* ws = (char*)d_ws;
    __bf16* Wb = (__bf16*)ws;
    __bf16* Xb = (__bf16*)(ws + (size_t)32 * 1024 * 1024);

    const int wElems = N * K;                    // 16777216
    const int xElems = M * K;                    // 33554432
    const int n8 = xElems / 8;                   // 4194304 cvt threads
    const int cvtBlocks = n8 / 256;              // 16384
    const int scatBlocks = (nnz + 255) / 256;    // 6554

    hipMemsetAsync(Wb, 0, (size_t)wElems * sizeof(__bf16), stream);
    // scatter blocks first: latency-bound random stores start immediately and
    // hide under the 16384 BW-bound cvt blocks.
    cvt_and_scatter<<<scatBlocks + cvtBlocks, 256, 0, stream>>>(
        x, Xb, n8, vals, idx, Wb, nnz, scatBlocks);

    gemm_bf16_bt<<<(M / BM) * (N / BN), 512, 0, stream>>>(Xb, Wb, bias, out, M, N, K);
}